// Round 11
// baseline (2938.485 us; speedup 1.0000x reference)
//
#include <hip/hip_runtime.h>
#include <cstdint>
#include <cstddef>

#define DIM 256
#define SLOPE 0.2f
#define BSHIFT 8          // 256 rows per bucket
#define SLOTS 9216        // per-bucket capacity: mean 8192 + ~11 sigma slack
#define TILE 4096         // edges per bin_edges block

typedef __attribute__((ext_vector_type(8))) short short8;  // 8 bf16 (4 VGPRs)
typedef __attribute__((ext_vector_type(4))) float f32x4;   // 4 fp32 acc

__device__ __forceinline__ unsigned short f2bf(float f) {  // RNE fp32->bf16
  unsigned u = __float_as_uint(f);
  u += 0x7fffu + ((u >> 16) & 1u);
  return (unsigned short)(u >> 16);
}
__device__ __forceinline__ float bf2f(unsigned short h) {
  return __uint_as_float(((unsigned)h) << 16);
}

// ---------------- bodies ----------------

__device__ __forceinline__ void bin_edges_body(
    int bx, int ty, int* hist, int* curs, const int* __restrict__ rr,
    const int* __restrict__ cc, int* __restrict__ bcnt, unsigned* __restrict__ pairs,
    int E, int NB) {
  const int t = threadIdx.x;
  const int base = bx * TILE;
  for (int i = t; i < NB; i += 256) hist[i] = 0;
  __syncthreads();
  int rows[TILE / 256];
#pragma unroll
  for (int i = 0; i < TILE / 256; ++i) {
    int e = base + t + i * 256;
    int r = (e < E) ? rr[e] : -1;
    rows[i] = r;
    if (r >= 0) atomicAdd(&hist[r >> BSHIFT], 1);
  }
  __syncthreads();
  for (int b = t; b < NB; b += 256) {
    int h = hist[b];
    int off = h ? atomicAdd(&bcnt[ty * NB + b], h) : 0;
    curs[b] = b * SLOTS + off;
  }
  __syncthreads();
  unsigned* pt = pairs + (size_t)ty * NB * SLOTS;
#pragma unroll
  for (int i = 0; i < TILE / 256; ++i) {
    int e = base + t + i * 256;
    if (e >= E) continue;
    int r = rows[i];
    int b = r >> BSHIFT;
    int pos = atomicAdd(&curs[b], 1);
    if (pos - b * SLOTS < SLOTS)
      pt[pos] = ((unsigned)(r & 255) << 17) | (unsigned)cc[e];
  }
}

__device__ __forceinline__ void bsort_body(
    int b, int ty, char* smem, const int* __restrict__ bcnt,
    unsigned* __restrict__ pairs, int* __restrict__ rp, int* __restrict__ deg,
    int N, int NB) {
  int* hist = (int*)smem;
  int* excl = hist + 256;
  int* curs = excl + 256;
  unsigned* stage = (unsigned*)(curs + 256);
  const int t = threadIdx.x;
  int cnt = bcnt[ty * NB + b];
  if (cnt > SLOTS) cnt = SLOTS;
  unsigned* pb = pairs + (size_t)ty * NB * SLOTS + (size_t)b * SLOTS;
  hist[t] = 0;
  __syncthreads();
  for (int i = t; i < cnt; i += 256) atomicAdd(&hist[pb[i] >> 17], 1);
  __syncthreads();
  int v = hist[t];
  excl[t] = v;
  __syncthreads();
  for (int off = 1; off < 256; off <<= 1) {
    int u = (t >= off) ? excl[t - off] : 0;
    __syncthreads();
    excl[t] += u;
    __syncthreads();
  }
  int ex = excl[t] - v;
  curs[t] = ex;
  int r = (b << BSHIFT) + t;
  if (r < N) {
    rp[(size_t)ty * N + r] = b * SLOTS + ex;
    deg[(size_t)ty * N + r] = v;
  }
  __syncthreads();
  for (int i = t; i < cnt; i += 256) {
    unsigned p = pb[i];
    int pos = atomicAdd(&curs[p >> 17], 1);
    stage[pos] = p;
  }
  __syncthreads();
  for (int i = t; i < cnt; i += 256) pb[i] = stage[i];
}

// gemm v2 body: 128-row tile, 4 waves x 32 rows/wave, 2 MFMA per B-load.
// tycount selects how many leading types to compute (1 => t0 only).
__device__ __forceinline__ void gemm3_body(
    int bx, char* smem, const float* __restrict__ H, const unsigned short* __restrict__ Wt,
    const float* __restrict__ a0, const float* __restrict__ a1,
    const float* __restrict__ a2, unsigned short* __restrict__ Whb,
    float* __restrict__ s_dst, float* __restrict__ s_src, int N, size_t wstride,
    int tycount) {
  unsigned short(*Hs)[264] = (unsigned short(*)[264])smem;
  unsigned short(*Os)[4][264] = (unsigned short(*)[4][264])(smem + 128 * 264 * 2);
  const int t = threadIdx.x;
  const int r0 = bx * 128;
#pragma unroll
  for (int i = 0; i < 32; ++i) {
    int idx = t + i * 256;
    int row = idx >> 6;
    int c4 = idx & 63;
    int r = r0 + row;
    float4 h = (r < N) ? *(const float4*)&H[(size_t)r * DIM + c4 * 4]
                       : make_float4(0.f, 0.f, 0.f, 0.f);
    unsigned lo = (unsigned)f2bf(h.x) | ((unsigned)f2bf(h.y) << 16);
    unsigned hi = (unsigned)f2bf(h.z) | ((unsigned)f2bf(h.w) << 16);
    *(uint2*)&Hs[row][c4 * 4] = make_uint2(lo, hi);
  }
  __syncthreads();
  const int wave = t >> 6, lane = t & 63;
  const int q = lane >> 4, m = lane & 15;
  const int rowbase = wave * 32;
  short8 Af0[8], Af1[8];
#pragma unroll
  for (int k0 = 0; k0 < 8; ++k0) {
    Af0[k0] = *(const short8*)&Hs[rowbase + m][k0 * 32 + q * 8];
    Af1[k0] = *(const short8*)&Hs[rowbase + 16 + m][k0 * 32 + q * 8];
  }
  const float* aptr[3] = {a0, a1, a2};
  for (int ty = 0; ty < tycount; ++ty) {
    const unsigned short* Wtt = Wt + (size_t)ty * DIM * DIM;
    const float* a = aptr[ty];
    f32x4 acc0[16], acc1[16];
#pragma unroll
    for (int j = 0; j < 16; ++j) {
      acc0[j] = (f32x4){0.f, 0.f, 0.f, 0.f};
      acc1[j] = (f32x4){0.f, 0.f, 0.f, 0.f};
    }
#pragma unroll
    for (int k0 = 0; k0 < 8; ++k0) {
#pragma unroll
      for (int j = 0; j < 16; ++j) {
        short8 Bf = *(const short8*)&Wtt[(size_t)(j * 16 + m) * DIM + k0 * 32 + q * 8];
        acc0[j] = __builtin_amdgcn_mfma_f32_16x16x32_bf16(Af0[k0], Bf, acc0[j], 0, 0, 0);
        acc1[j] = __builtin_amdgcn_mfma_f32_16x16x32_bf16(Af1[k0], Bf, acc1[j], 0, 0, 0);
      }
    }
    float pd0[4] = {0, 0, 0, 0}, ps0[4] = {0, 0, 0, 0};
    float pd1[4] = {0, 0, 0, 0}, ps1[4] = {0, 0, 0, 0};
#pragma unroll
    for (int j = 0; j < 16; ++j) {
      int col = j * 16 + m;
      float ad = a[col], as = a[DIM + col];
#pragma unroll
      for (int reg = 0; reg < 4; ++reg) {
        float v0 = acc0[j][reg], v1 = acc1[j][reg];
        pd0[reg] += v0 * ad;
        ps0[reg] += v0 * as;
        pd1[reg] += v1 * ad;
        ps1[reg] += v1 * as;
      }
    }
#pragma unroll
    for (int off = 8; off >= 1; off >>= 1) {
#pragma unroll
      for (int reg = 0; reg < 4; ++reg) {
        pd0[reg] += __shfl_down(pd0[reg], off);
        ps0[reg] += __shfl_down(ps0[reg], off);
        pd1[reg] += __shfl_down(pd1[reg], off);
        ps1[reg] += __shfl_down(ps1[reg], off);
      }
    }
    if (m == 0) {
#pragma unroll
      for (int reg = 0; reg < 4; ++reg) {
        int ra = r0 + rowbase + q * 4 + reg;
        int rb = ra + 16;
        if (ra < N) {
          s_dst[(size_t)ty * N + ra] = pd0[reg];
          s_src[(size_t)ty * N + ra] = ps0[reg];
        }
        if (rb < N) {
          s_dst[(size_t)ty * N + rb] = pd1[reg];
          s_src[(size_t)ty * N + rb] = ps1[reg];
        }
      }
    }
    unsigned short* wout = Whb + (size_t)ty * wstride;
#pragma unroll
    for (int g = 0; g < 2; ++g) {
#pragma unroll
      for (int p = 0; p < 4; ++p) {
        if (q == p) {
#pragma unroll
          for (int j = 0; j < 16; ++j)
#pragma unroll
            for (int reg = 0; reg < 4; ++reg)
              Os[wave][reg][j * 16 + m] = f2bf(g ? acc1[j][reg] : acc0[j][reg]);
        }
#pragma unroll
        for (int rr = 0; rr < 4; ++rr) {
          int r = r0 + rowbase + g * 16 + p * 4 + rr;
          if (r < N)
            *(uint2*)&wout[(size_t)r * DIM + lane * 4] =
                *(const uint2*)&Os[wave][rr][lane * 4];
        }
      }
    }
  }
}

// LEAN per-type gemm for überC: 64-row tile, 16 rows/wave, j-split halves
// (acc[8]) to fit <=128 VGPR; A-fragments straight from global H (L3-hot);
// Os only 8.4 KB so co-resident gat blocks keep occupancy.
__device__ __forceinline__ void gemm1_lean_body(
    int bx, int ty, char* smem, const float* __restrict__ H,
    const unsigned short* __restrict__ Wt, const float* __restrict__ a,
    unsigned short* __restrict__ Whb, float* __restrict__ s_dst,
    float* __restrict__ s_src, int N, size_t wstride) {
  unsigned short(*Os)[4][264] = (unsigned short(*)[4][264])smem;  // 8448 B
  const int t = threadIdx.x;
  const int r0 = bx * 64;
  const int wave = t >> 6, lane = t & 63;
  const int q = lane >> 4, m = lane & 15;
  const int rowbase = wave * 16;
  const int myrow = r0 + rowbase + m;
  short8 Af[8];
#pragma unroll
  for (int k0 = 0; k0 < 8; ++k0) {
    short8 v = (short8){0, 0, 0, 0, 0, 0, 0, 0};
    if (myrow < N) {
      const float* hp = &H[(size_t)myrow * DIM + k0 * 32 + q * 8];
      float4 x = *(const float4*)hp;
      float4 y = *(const float4*)(hp + 4);
      v[0] = (short)f2bf(x.x); v[1] = (short)f2bf(x.y);
      v[2] = (short)f2bf(x.z); v[3] = (short)f2bf(x.w);
      v[4] = (short)f2bf(y.x); v[5] = (short)f2bf(y.y);
      v[6] = (short)f2bf(y.z); v[7] = (short)f2bf(y.w);
    }
    Af[k0] = v;
  }
  const unsigned short* Wtt = Wt + (size_t)ty * DIM * DIM;
  unsigned short* wout = Whb + (size_t)ty * wstride;
  float pd[4] = {0, 0, 0, 0}, ps[4] = {0, 0, 0, 0};
  for (int jh = 0; jh < 2; ++jh) {
    f32x4 acc[8];
#pragma unroll
    for (int j = 0; j < 8; ++j) acc[j] = (f32x4){0.f, 0.f, 0.f, 0.f};
#pragma unroll
    for (int k0 = 0; k0 < 8; ++k0) {
#pragma unroll
      for (int j = 0; j < 8; ++j) {
        int col16 = jh * 8 + j;
        short8 Bf = *(const short8*)&Wtt[(size_t)(col16 * 16 + m) * DIM + k0 * 32 + q * 8];
        acc[j] = __builtin_amdgcn_mfma_f32_16x16x32_bf16(Af[k0], Bf, acc[j], 0, 0, 0);
      }
    }
#pragma unroll
    for (int j = 0; j < 8; ++j) {
      int col = (jh * 8 + j) * 16 + m;
      float ad = a[col], as = a[DIM + col];
#pragma unroll
      for (int reg = 0; reg < 4; ++reg) {
        float v = acc[j][reg];
        pd[reg] += v * ad;
        ps[reg] += v * as;
      }
    }
    // half-row (128-col) stores via 4-row wave-private Os passes
#pragma unroll
    for (int p = 0; p < 4; ++p) {
      if (q == p) {
#pragma unroll
        for (int j = 0; j < 8; ++j)
#pragma unroll
          for (int reg = 0; reg < 4; ++reg)
            Os[wave][reg][(jh * 8 + j) * 16 + m] = f2bf(acc[j][reg]);
      }
#pragma unroll
      for (int rr = 0; rr < 4; ++rr) {
        int r = r0 + rowbase + p * 4 + rr;
        if (r < N)
          *(unsigned*)&wout[(size_t)r * DIM + jh * 128 + lane * 2] =
              *(const unsigned*)&Os[wave][rr][jh * 128 + lane * 2];
      }
    }
  }
#pragma unroll
  for (int off = 8; off >= 1; off >>= 1) {
#pragma unroll
    for (int reg = 0; reg < 4; ++reg) {
      pd[reg] += __shfl_down(pd[reg], off);
      ps[reg] += __shfl_down(ps[reg], off);
    }
  }
  if (m == 0) {
#pragma unroll
    for (int reg = 0; reg < 4; ++reg) {
      int r = r0 + rowbase + q * 4 + reg;
      if (r < N) {
        s_dst[(size_t)ty * N + r] = pd[reg];
        s_src[(size_t)ty * N + r] = ps[reg];
      }
    }
  }
}

// ---------------- kernels ----------------

// überA: wtrans (768 blocks) ∥ bin_edges (3*eb blocks)
__global__ __launch_bounds__(256) void prep_kernel(
    const float* __restrict__ W0, const float* __restrict__ W1,
    const float* __restrict__ W2, unsigned short* __restrict__ Wt,
    const int* __restrict__ r0, const int* __restrict__ r1, const int* __restrict__ r2,
    const int* __restrict__ c0, const int* __restrict__ c1, const int* __restrict__ c2,
    int* __restrict__ bcnt, unsigned* __restrict__ pairs, int E, int NB, int eb) {
  __shared__ int smem[1024];
  const int bx = blockIdx.x;
  if (bx < 768) {
    int ty = bx >> 8, k = bx & 255, n = threadIdx.x;
    const float* W = ty == 0 ? W0 : (ty == 1 ? W1 : W2);
    Wt[((size_t)ty * DIM + n) * DIM + k] = f2bf(W[k * DIM + n]);
    return;
  }
  int e2 = bx - 768;
  int ty = e2 / eb, bxx = e2 % eb;
  const int* rr = ty == 0 ? r0 : (ty == 1 ? r1 : r2);
  const int* cc = ty == 0 ? c0 : (ty == 1 ? c1 : c2);
  bin_edges_body(bxx, ty, smem, smem + 512, rr, cc, bcnt, pairs, E, NB);
}

// überB: gemm-v2(t0 only) ∥ bucket_sort(all 3 types)
__global__ __launch_bounds__(256, 2) void compute_kernel(
    const float* __restrict__ H, const unsigned short* __restrict__ Wt,
    const float* __restrict__ a0, const float* __restrict__ a1,
    const float* __restrict__ a2, unsigned short* __restrict__ Whb,
    float* __restrict__ s_dst, float* __restrict__ s_src, int N, size_t wstride,
    const int* __restrict__ bcnt, unsigned* __restrict__ pairs,
    int* __restrict__ rp, int* __restrict__ deg, int NB, int gemm_blocks,
    int tycount) {
  __shared__ __align__(16) char smem[76032];
  const int bx = blockIdx.x;
  if (bx < gemm_blocks) {
    gemm3_body(bx, smem, H, Wt, a0, a1, a2, Whb, s_dst, s_src, N, wstride, tycount);
  } else {
    int e = bx - gemm_blocks;
    bsort_body(e % NB, e / NB, smem, bcnt, pairs, rp, deg, N, NB);
  }
}

// überC: gat(t0, first-write) ∥ gemm-lean(t1,t2), interleaved 1-per-R blocks.
// launch_bounds(256,4) pins VGPR<=128 -> >=16 waves/CU for the gat side.
__global__ __launch_bounds__(256, 4) void gat0_gemm_kernel(
    const float* __restrict__ H, const unsigned short* __restrict__ Wt,
    const float* __restrict__ a1, const float* __restrict__ a2,
    unsigned short* __restrict__ Whb, float* __restrict__ s_dst,
    float* __restrict__ s_src, const int* __restrict__ rp, const int* __restrict__ deg,
    const unsigned* __restrict__ pairs, const float* __restrict__ bias,
    float* __restrict__ out, int N, size_t wstride, int gemmB, int R) {
  __shared__ __align__(16) char smem[8448];
  const int bx = blockIdx.x;
  int g = bx / R;
  if (bx - g * R == 0 && g < gemmB) {
    int ty = 1 + (g & 1);
    gemm1_lean_body(g >> 1, ty, smem, H, Wt, (ty == 1 ? a1 : a2), Whb, s_dst, s_src, N,
                    wstride);
    return;
  }
  int gidx = (g < gemmB) ? (bx - g - 1) : (bx - gemmB);
  int n = gidx * 4 + (threadIdx.x >> 6);
  if (n >= N) return;
  uint2(*ebuf)[64] = (uint2(*)[64])smem;
  const int wid = threadIdx.x >> 6;
  const int lane = threadIdx.x & 63;
  int beg = rp[n], d = deg[n], end = beg + d;
  float sd = s_dst[n];
  float mx = -__builtin_inff();
  for (int p = beg + lane; p < end; p += 64) {
    float v = sd + s_src[pairs[p] & 0x1FFFFu];
    v = v > 0.f ? v : SLOPE * v;
    mx = fmaxf(mx, v);
  }
#pragma unroll
  for (int off = 32; off >= 1; off >>= 1) mx = fmaxf(mx, __shfl_down(mx, off));
  mx = __shfl(mx, 0);
  const unsigned short* wbase = Whb + lane * 4;
  float4 acc = {0.f, 0.f, 0.f, 0.f};
  float psum = 0.f;
  for (int base = beg; base < end; base += 64) {
    int myp = base + lane;
    int cnt = end - base;
    if (cnt > 64) cnt = 64;
    unsigned myc = 0;
    float mype = 0.f;
    if (myp < end) {
      myc = pairs[myp] & 0x1FFFFu;
      float v = sd + s_src[myc];
      v = v > 0.f ? v : SLOPE * v;
      mype = __expf(v - mx);
    }
    psum += mype;
    ebuf[wid][lane] = make_uint2(myc, __float_as_uint(mype));
#pragma unroll 8
    for (int j = 0; j < cnt; ++j) {
      uint2 cp = ebuf[wid][j];
      float pe = __uint_as_float(cp.y);
      ushort4 w = *(const ushort4*)&wbase[(size_t)cp.x * DIM];
      acc.x += pe * bf2f(w.x);
      acc.y += pe * bf2f(w.y);
      acc.z += pe * bf2f(w.z);
      acc.w += pe * bf2f(w.w);
    }
  }
#pragma unroll
  for (int off = 32; off >= 1; off >>= 1) psum += __shfl_down(psum, off);
  psum = __shfl(psum, 0);
  float inv = 1.f / fmaxf(psum, 1e-12f);
  float4 cur = ((const float4*)bias)[lane];
  cur.x += acc.x * inv;
  cur.y += acc.y * inv;
  cur.z += acc.z * inv;
  cur.w += acc.w * inv;
  *((float4*)(out + (size_t)n * DIM) + lane) = cur;
}

// überD: gat t1+t2 in-register, single RMW of out.
__global__ __launch_bounds__(256) void gat12_kernel(
    const int* __restrict__ rp, const int* __restrict__ deg,
    const unsigned* __restrict__ pairs,
    const float* __restrict__ s_dst, const float* __restrict__ s_src,
    const unsigned short* __restrict__ Whb, float* __restrict__ out, int N, int NB,
    size_t wstride) {
  __shared__ uint2 ebuf[4][64];
  int n = (int)((blockIdx.x * (unsigned)blockDim.x + threadIdx.x) >> 6);
  if (n >= N) return;
  const int wid = (threadIdx.x >> 6);
  const int lane = threadIdx.x & 63;
  float4 total = {0.f, 0.f, 0.f, 0.f};
  int any = 0;
  for (int t = 1; t < 3; ++t) {
    int beg = rp[(size_t)t * N + n], d = deg[(size_t)t * N + n];
    if (d == 0) continue;
    any = 1;
    int end = beg + d;
    const unsigned* pcol = pairs + (size_t)t * NB * SLOTS;
    const float* ss = s_src + (size_t)t * N;
    float sd = s_dst[(size_t)t * N + n];
    const unsigned short* wbase = Whb + (size_t)t * wstride + lane * 4;
    float mx = -__builtin_inff();
    for (int p = beg + lane; p < end; p += 64) {
      float v = sd + ss[pcol[p] & 0x1FFFFu];
      v = v > 0.f ? v : SLOPE * v;
      mx = fmaxf(mx, v);
    }
#pragma unroll
    for (int off = 32; off >= 1; off >>= 1) mx = fmaxf(mx, __shfl_down(mx, off));
    mx = __shfl(mx, 0);
    float4 acc = {0.f, 0.f, 0.f, 0.f};
    float psum = 0.f;
    for (int base = beg; base < end; base += 64) {
      int myp = base + lane;
      int cnt = end - base;
      if (cnt > 64) cnt = 64;
      unsigned myc = 0;
      float mype = 0.f;
      if (myp < end) {
        myc = pcol[myp] & 0x1FFFFu;
        float v = sd + ss[myc];
        v = v > 0.f ? v : SLOPE * v;
        mype = __expf(v - mx);
      }
      psum += mype;
      ebuf[wid][lane] = make_uint2(myc, __float_as_uint(mype));
#pragma unroll 8
      for (int j = 0; j < cnt; ++j) {
        uint2 cp = ebuf[wid][j];
        float pe = __uint_as_float(cp.y);
        ushort4 w = *(const ushort4*)&wbase[(size_t)cp.x * DIM];
        acc.x += pe * bf2f(w.x);
        acc.y += pe * bf2f(w.y);
        acc.z += pe * bf2f(w.z);
        acc.w += pe * bf2f(w.w);
      }
    }
#pragma unroll
    for (int off = 32; off >= 1; off >>= 1) psum += __shfl_down(psum, off);
    psum = __shfl(psum, 0);
    float inv = 1.f / fmaxf(psum, 1e-12f);
    total.x += acc.x * inv;
    total.y += acc.y * inv;
    total.z += acc.z * inv;
    total.w += acc.w * inv;
  }
  if (!any) return;
  float4* o = (float4*)(out + (size_t)n * DIM) + lane;
  float4 cur = *o;
  cur.x += total.x;
  cur.y += total.y;
  cur.z += total.z;
  cur.w += total.w;
  *o = cur;
}

// ---------------- fallback kernels (small workspace) ----------------

__global__ __launch_bounds__(256) void bucket_sort_kernel(
    const int* __restrict__ bcnt, unsigned* __restrict__ pairs,
    int* __restrict__ rp, int* __restrict__ deg, int N, int NB) {
  __shared__ __align__(16) char smem[39936];
  bsort_body(blockIdx.x, blockIdx.y, smem, bcnt, pairs, rp, deg, N, NB);
}

__global__ __launch_bounds__(256, 2) void gemm_scores_kernel(
    const float* __restrict__ H, const unsigned short* __restrict__ Wt,
    const float* __restrict__ a, unsigned short* __restrict__ Whb,
    float* __restrict__ s_dst, float* __restrict__ s_src, int N) {
  __shared__ unsigned short Hs[64][264];
  __shared__ unsigned short Os[4][16][264];
  const int t = threadIdx.x;
  const int r0 = blockIdx.x * 64;
#pragma unroll
  for (int i = 0; i < 16; ++i) {
    int idx = t + i * 256;
    int row = idx >> 6;
    int c4 = idx & 63;
    int r = r0 + row;
    float4 h = (r < N) ? *(const float4*)&H[(size_t)r * DIM + c4 * 4]
                       : make_float4(0.f, 0.f, 0.f, 0.f);
    unsigned lo = (unsigned)f2bf(h.x) | ((unsigned)f2bf(h.y) << 16);
    unsigned hi = (unsigned)f2bf(h.z) | ((unsigned)f2bf(h.w) << 16);
    *(uint2*)&Hs[row][c4 * 4] = make_uint2(lo, hi);
  }
  __syncthreads();
  const int wave = t >> 6, lane = t & 63;
  const int q = lane >> 4, m = lane & 15;
  const int rowbase = wave * 16;
  short8 Af[8];
#pragma unroll
  for (int k0 = 0; k0 < 8; ++k0)
    Af[k0] = *(const short8*)&Hs[rowbase + m][k0 * 32 + q * 8];
  f32x4 acc[16];
#pragma unroll
  for (int j = 0; j < 16; ++j) acc[j] = (f32x4){0.f, 0.f, 0.f, 0.f};
#pragma unroll
  for (int k0 = 0; k0 < 8; ++k0) {
#pragma unroll
    for (int j = 0; j < 16; ++j) {
      short8 Bf = *(const short8*)&Wt[(size_t)(j * 16 + m) * DIM + k0 * 32 + q * 8];
      acc[j] = __builtin_amdgcn_mfma_f32_16x16x32_bf16(Af[k0], Bf, acc[j], 0, 0, 0);
    }
  }
  float pd[4] = {0, 0, 0, 0}, ps[4] = {0, 0, 0, 0};
#pragma unroll
  for (int j = 0; j < 16; ++j) {
    int col = j * 16 + m;
    float ad = a[col], as = a[DIM + col];
#pragma unroll
    for (int reg = 0; reg < 4; ++reg) {
      float v = acc[j][reg];
      pd[reg] += v * ad;
      ps[reg] += v * as;
      Os[wave][q * 4 + reg][col] = f2bf(v);
    }
  }
#pragma unroll
  for (int off = 8; off >= 1; off >>= 1) {
#pragma unroll
    for (int reg = 0; reg < 4; ++reg) {
      pd[reg] += __shfl_down(pd[reg], off);
      ps[reg] += __shfl_down(ps[reg], off);
    }
  }
  if (m == 0) {
#pragma unroll
    for (int reg = 0; reg < 4; ++reg) {
      int r = r0 + rowbase + q * 4 + reg;
      if (r < N) {
        s_dst[r] = pd[reg];
        s_src[r] = ps[reg];
      }
    }
  }
  __syncthreads();
#pragma unroll
  for (int row = 0; row < 16; ++row) {
    int r = r0 + rowbase + row;
    if (r < N)
      *(uint2*)&Whb[(size_t)r * DIM + lane * 4] = *(const uint2*)&Os[wave][row][lane * 4];
  }
}

__global__ __launch_bounds__(256) void gat_node_kernel(
    const int* __restrict__ rp, const int* __restrict__ deg,
    const unsigned* __restrict__ pcol,
    const float* __restrict__ s_dst, const float* __restrict__ s_src,
    const unsigned short* __restrict__ Whb,
    const float* __restrict__ bias, float* __restrict__ out, int N, int first) {
  __shared__ uint2 ebuf[4][64];
  int n = (int)((blockIdx.x * (unsigned)blockDim.x + threadIdx.x) >> 6);
  if (n >= N) return;
  const int wid = (threadIdx.x >> 6);
  const int lane = threadIdx.x & 63;
  int beg = rp[n], d = deg[n], end = beg + d;
  if (!first && d == 0) return;
  float sd = s_dst[n];
  float mx = -__builtin_inff();
  for (int p = beg + lane; p < end; p += 64) {
    float v = sd + s_src[pcol[p] & 0x1FFFFu];
    v = v > 0.f ? v : SLOPE * v;
    mx = fmaxf(mx, v);
  }
#pragma unroll
  for (int off = 32; off >= 1; off >>= 1) mx = fmaxf(mx, __shfl_down(mx, off));
  mx = __shfl(mx, 0);
  const unsigned short* wbase = Whb + lane * 4;
  float4 acc = {0.f, 0.f, 0.f, 0.f};
  float psum = 0.f;
  for (int base = beg; base < end; base += 64) {
    int myp = base + lane;
    int cnt = end - base;
    if (cnt > 64) cnt = 64;
    unsigned myc = 0;
    float mype = 0.f;
    if (myp < end) {
      myc = pcol[myp] & 0x1FFFFu;
      float v = sd + s_src[myc];
      v = v > 0.f ? v : SLOPE * v;
      mype = __expf(v - mx);
    }
    psum += mype;
    ebuf[wid][lane] = make_uint2(myc, __float_as_uint(mype));
#pragma unroll 8
    for (int j = 0; j < cnt; ++j) {
      uint2 cp = ebuf[wid][j];
      float pe = __uint_as_float(cp.y);
      ushort4 w = *(const ushort4*)&wbase[(size_t)cp.x * DIM];
      acc.x += pe * bf2f(w.x);
      acc.y += pe * bf2f(w.y);
      acc.z += pe * bf2f(w.z);
      acc.w += pe * bf2f(w.w);
    }
  }
#pragma unroll
  for (int off = 32; off >= 1; off >>= 1) psum += __shfl_down(psum, off);
  psum = __shfl(psum, 0);
  float inv = 1.f / fmaxf(psum, 1e-12f);
  float4* o = (float4*)(out + (size_t)n * DIM) + lane;
  float4 cur = first ? ((const float4*)bias)[lane] : *o;
  cur.x += acc.x * inv;
  cur.y += acc.y * inv;
  cur.z += acc.z * inv;
  cur.w += acc.w * inv;
  *o = cur;
}

static inline size_t align256(size_t x) { return (x + 255) & ~(size_t)255; }

extern "C" void kernel_launch(void* const* d_in, const int* in_sizes, int n_in,
                              void* d_out, int out_size, void* d_ws, size_t ws_size,
                              hipStream_t stream) {
  const float* H = (const float*)d_in[0];
  const float* W[3] = {(const float*)d_in[1], (const float*)d_in[2], (const float*)d_in[3]};
  const float* a[3] = {(const float*)d_in[4], (const float*)d_in[5], (const float*)d_in[6]};
  const float* bias = (const float*)d_in[7];
  const int* row[3] = {(const int*)d_in[8], (const int*)d_in[10], (const int*)d_in[12]};
  const int* col[3] = {(const int*)d_in[9], (const int*)d_in[11], (const int*)d_in[13]};
  const int N = in_sizes[0] / DIM;
  const int E = in_sizes[8];
  const int NB = (N + 255) >> BSHIFT;  // 391 for N=100000 (must be <= 512)
  float* out = (float*)d_out;

  char* ws = (char*)d_ws;
  size_t off = 0;
  unsigned short* Wt = (unsigned short*)(ws + off);
  off = align256(off + (size_t)3 * DIM * DIM * sizeof(unsigned short));
  float* s_dst = (float*)(ws + off);  // [3][N]
  off = align256(off + (size_t)3 * N * sizeof(float));
  float* s_src = (float*)(ws + off);  // [3][N]
  off = align256(off + (size_t)3 * N * sizeof(float));
  int* bcnt = (int*)(ws + off);
  off = align256(off + (size_t)3 * NB * sizeof(int));
  int* rp = (int*)(ws + off);
  off = align256(off + (size_t)3 * N * sizeof(int));
  int* deg = (int*)(ws + off);
  off = align256(off + (size_t)3 * N * sizeof(int));
  unsigned* pairs = (unsigned*)(ws + off);
  off = align256(off + (size_t)3 * NB * SLOTS * sizeof(unsigned));
  unsigned short* Whb = (unsigned short*)(ws + off);
  const size_t whb_bytes = align256((size_t)N * DIM * sizeof(unsigned short));
  const size_t wstride = whb_bytes / sizeof(unsigned short);
  const int fused = (ws_size >= off + 3 * whb_bytes) ? 1 : 0;

  const int eb = (E + TILE - 1) / TILE;
  hipMemsetAsync(bcnt, 0, (size_t)3 * NB * sizeof(int), stream);
  prep_kernel<<<768 + 3 * eb, 256, 0, stream>>>(W[0], W[1], W[2], Wt, row[0], row[1], row[2],
                                                col[0], col[1], col[2], bcnt, pairs, E, NB, eb);

  const int gat_blocks = (N * 64 + 255) / 256;
  if (fused) {
    const int nb128 = (N + 127) / 128;
    compute_kernel<<<nb128 + 3 * NB, 256, 0, stream>>>(
        H, Wt, a[0], a[1], a[2], Whb, s_dst, s_src, N, wstride, bcnt, pairs, rp, deg, NB,
        nb128, 1 /* gemm t0 only */);
    const int nb64 = (N + 63) / 64;
    const int gemmB = 2 * nb64;
    int R = gat_blocks / gemmB + 1;
    if (R < 2) R = 2;
    const int gridC = gat_blocks + gemmB + R;
    gat0_gemm_kernel<<<gridC, 256, 0, stream>>>(H, Wt, a[1], a[2], Whb, s_dst, s_src, rp, deg,
                                                pairs, bias, out, N, wstride, gemmB, R);
    gat12_kernel<<<gat_blocks, 256, 0, stream>>>(rp, deg, pairs, s_dst, s_src, Whb, out, N,
                                                 NB, wstride);
  } else {
    bucket_sort_kernel<<<dim3(NB, 3), 256, 0, stream>>>(bcnt, pairs, rp, deg, N, NB);
    for (int t = 0; t < 3; ++t) {
      gemm_scores_kernel<<<(N + 63) / 64, 256, 0, stream>>>(H, Wt + (size_t)t * DIM * DIM,
                                                            a[t], Whb, s_dst + (size_t)t * N,
                                                            s_src + (size_t)t * N, N);
      gat_node_kernel<<<gat_blocks, 256, 0, stream>>>(
          rp + (size_t)t * N, deg + (size_t)t * N, pairs + (size_t)t * NB * SLOTS,
          s_dst + (size_t)t * N, s_src + (size_t)t * N, Whb, bias, out, N, t == 0 ? 1 : 0);
    }
  }
  (void)n_in;
  (void)out_size;
  (void)ws_size;
}

// Round 12
// 1415.574 us; speedup vs baseline: 2.0758x; 2.0758x over previous
//
#include <hip/hip_runtime.h>
#include <cstdint>
#include <cstddef>

#define DIM 256
#define SLOPE 0.2f
#define BSHIFT 8          // 256 rows per bucket
#define SLOTS 9216        // per-bucket capacity: mean 8192 + ~11 sigma slack
#define TILE 4096         // edges per bin_edges block

typedef __attribute__((ext_vector_type(8))) short short8;  // 8 bf16 (4 VGPRs)
typedef __attribute__((ext_vector_type(4))) float f32x4;   // 4 fp32 acc

__device__ __forceinline__ unsigned short f2bf(float f) {  // RNE fp32->bf16
  unsigned u = __float_as_uint(f);
  u += 0x7fffu + ((u >> 16) & 1u);
  return (unsigned short)(u >> 16);
}
__device__ __forceinline__ float bf2f(unsigned short h) {
  return __uint_as_float(((unsigned)h) << 16);
}

// ---------------- bodies ----------------

__device__ __forceinline__ void bin_edges_body(
    int bx, int ty, int* hist, int* curs, const int* __restrict__ rr,
    const int* __restrict__ cc, int* __restrict__ bcnt, unsigned* __restrict__ pairs,
    int E, int NB) {
  const int t = threadIdx.x;
  const int base = bx * TILE;
  for (int i = t; i < NB; i += 256) hist[i] = 0;
  __syncthreads();
  int rows[TILE / 256];
#pragma unroll
  for (int i = 0; i < TILE / 256; ++i) {
    int e = base + t + i * 256;
    int r = (e < E) ? rr[e] : -1;
    rows[i] = r;
    if (r >= 0) atomicAdd(&hist[r >> BSHIFT], 1);
  }
  __syncthreads();
  for (int b = t; b < NB; b += 256) {
    int h = hist[b];
    int off = h ? atomicAdd(&bcnt[ty * NB + b], h) : 0;
    curs[b] = b * SLOTS + off;
  }
  __syncthreads();
  unsigned* pt = pairs + (size_t)ty * NB * SLOTS;
#pragma unroll
  for (int i = 0; i < TILE / 256; ++i) {
    int e = base + t + i * 256;
    if (e >= E) continue;
    int r = rows[i];
    int b = r >> BSHIFT;
    int pos = atomicAdd(&curs[b], 1);
    if (pos - b * SLOTS < SLOTS)
      pt[pos] = ((unsigned)(r & 255) << 17) | (unsigned)cc[e];
  }
}

__device__ __forceinline__ void bsort_body(
    int b, int ty, char* smem, const int* __restrict__ bcnt,
    unsigned* __restrict__ pairs, int* __restrict__ rp, int* __restrict__ deg,
    int N, int NB) {
  int* hist = (int*)smem;
  int* excl = hist + 256;
  int* curs = excl + 256;
  unsigned* stage = (unsigned*)(curs + 256);
  const int t = threadIdx.x;
  int cnt = bcnt[ty * NB + b];
  if (cnt > SLOTS) cnt = SLOTS;
  unsigned* pb = pairs + (size_t)ty * NB * SLOTS + (size_t)b * SLOTS;
  hist[t] = 0;
  __syncthreads();
  for (int i = t; i < cnt; i += 256) atomicAdd(&hist[pb[i] >> 17], 1);
  __syncthreads();
  int v = hist[t];
  excl[t] = v;
  __syncthreads();
  for (int off = 1; off < 256; off <<= 1) {
    int u = (t >= off) ? excl[t - off] : 0;
    __syncthreads();
    excl[t] += u;
    __syncthreads();
  }
  int ex = excl[t] - v;
  curs[t] = ex;
  int r = (b << BSHIFT) + t;
  if (r < N) {
    rp[(size_t)ty * N + r] = b * SLOTS + ex;
    deg[(size_t)ty * N + r] = v;
  }
  __syncthreads();
  for (int i = t; i < cnt; i += 256) {
    unsigned p = pb[i];
    int pos = atomicAdd(&curs[p >> 17], 1);
    stage[pos] = p;
  }
  __syncthreads();
  for (int i = t; i < cnt; i += 256) pb[i] = stage[i];
}

// gemm3 v2 body: 128-row tile, 4 waves x 32 rows/wave, 2 MFMA per B-load.
__device__ __forceinline__ void gemm3_body(
    int bx, char* smem, const float* __restrict__ H, const unsigned short* __restrict__ Wt,
    const float* __restrict__ a0, const float* __restrict__ a1,
    const float* __restrict__ a2, unsigned short* __restrict__ Whb,
    float* __restrict__ s_dst, float* __restrict__ s_src, int N, size_t wstride) {
  unsigned short(*Hs)[264] = (unsigned short(*)[264])smem;
  unsigned short(*Os)[4][264] = (unsigned short(*)[4][264])(smem + 128 * 264 * 2);
  const int t = threadIdx.x;
  const int r0 = bx * 128;
#pragma unroll
  for (int i = 0; i < 32; ++i) {
    int idx = t + i * 256;
    int row = idx >> 6;
    int c4 = idx & 63;
    int r = r0 + row;
    float4 h = (r < N) ? *(const float4*)&H[(size_t)r * DIM + c4 * 4]
                       : make_float4(0.f, 0.f, 0.f, 0.f);
    unsigned lo = (unsigned)f2bf(h.x) | ((unsigned)f2bf(h.y) << 16);
    unsigned hi = (unsigned)f2bf(h.z) | ((unsigned)f2bf(h.w) << 16);
    *(uint2*)&Hs[row][c4 * 4] = make_uint2(lo, hi);
  }
  __syncthreads();
  const int wave = t >> 6, lane = t & 63;
  const int q = lane >> 4, m = lane & 15;
  const int rowbase = wave * 32;
  short8 Af0[8], Af1[8];
#pragma unroll
  for (int k0 = 0; k0 < 8; ++k0) {
    Af0[k0] = *(const short8*)&Hs[rowbase + m][k0 * 32 + q * 8];
    Af1[k0] = *(const short8*)&Hs[rowbase + 16 + m][k0 * 32 + q * 8];
  }
  const float* aptr[3] = {a0, a1, a2};
  for (int ty = 0; ty < 3; ++ty) {
    const unsigned short* Wtt = Wt + (size_t)ty * DIM * DIM;
    const float* a = aptr[ty];
    f32x4 acc0[16], acc1[16];
#pragma unroll
    for (int j = 0; j < 16; ++j) {
      acc0[j] = (f32x4){0.f, 0.f, 0.f, 0.f};
      acc1[j] = (f32x4){0.f, 0.f, 0.f, 0.f};
    }
#pragma unroll
    for (int k0 = 0; k0 < 8; ++k0) {
#pragma unroll
      for (int j = 0; j < 16; ++j) {
        short8 Bf = *(const short8*)&Wtt[(size_t)(j * 16 + m) * DIM + k0 * 32 + q * 8];
        acc0[j] = __builtin_amdgcn_mfma_f32_16x16x32_bf16(Af0[k0], Bf, acc0[j], 0, 0, 0);
        acc1[j] = __builtin_amdgcn_mfma_f32_16x16x32_bf16(Af1[k0], Bf, acc1[j], 0, 0, 0);
      }
    }
    float pd0[4] = {0, 0, 0, 0}, ps0[4] = {0, 0, 0, 0};
    float pd1[4] = {0, 0, 0, 0}, ps1[4] = {0, 0, 0, 0};
#pragma unroll
    for (int j = 0; j < 16; ++j) {
      int col = j * 16 + m;
      float ad = a[col], as = a[DIM + col];
#pragma unroll
      for (int reg = 0; reg < 4; ++reg) {
        float v0 = acc0[j][reg], v1 = acc1[j][reg];
        pd0[reg] += v0 * ad;
        ps0[reg] += v0 * as;
        pd1[reg] += v1 * ad;
        ps1[reg] += v1 * as;
      }
    }
#pragma unroll
    for (int off = 8; off >= 1; off >>= 1) {
#pragma unroll
      for (int reg = 0; reg < 4; ++reg) {
        pd0[reg] += __shfl_down(pd0[reg], off);
        ps0[reg] += __shfl_down(ps0[reg], off);
        pd1[reg] += __shfl_down(pd1[reg], off);
        ps1[reg] += __shfl_down(ps1[reg], off);
      }
    }
    if (m == 0) {
#pragma unroll
      for (int reg = 0; reg < 4; ++reg) {
        int ra = r0 + rowbase + q * 4 + reg;
        int rb = ra + 16;
        if (ra < N) {
          s_dst[(size_t)ty * N + ra] = pd0[reg];
          s_src[(size_t)ty * N + ra] = ps0[reg];
        }
        if (rb < N) {
          s_dst[(size_t)ty * N + rb] = pd1[reg];
          s_src[(size_t)ty * N + rb] = ps1[reg];
        }
      }
    }
    unsigned short* wout = Whb + (size_t)ty * wstride;
#pragma unroll
    for (int g = 0; g < 2; ++g) {
#pragma unroll
      for (int p = 0; p < 4; ++p) {
        if (q == p) {
#pragma unroll
          for (int j = 0; j < 16; ++j)
#pragma unroll
            for (int reg = 0; reg < 4; ++reg)
              Os[wave][reg][j * 16 + m] = f2bf(g ? acc1[j][reg] : acc0[j][reg]);
        }
#pragma unroll
        for (int rr = 0; rr < 4; ++rr) {
          int r = r0 + rowbase + g * 16 + p * 4 + rr;
          if (r < N)
            *(uint2*)&wout[(size_t)r * DIM + lane * 4] =
                *(const uint2*)&Os[wave][rr][lane * 4];
        }
      }
    }
  }
}

// ---------------- über kernels ----------------

// überA: wtrans (768 blocks) ∥ bin_edges (3*eb blocks)
__global__ __launch_bounds__(256) void prep_kernel(
    const float* __restrict__ W0, const float* __restrict__ W1,
    const float* __restrict__ W2, unsigned short* __restrict__ Wt,
    const int* __restrict__ r0, const int* __restrict__ r1, const int* __restrict__ r2,
    const int* __restrict__ c0, const int* __restrict__ c1, const int* __restrict__ c2,
    int* __restrict__ bcnt, unsigned* __restrict__ pairs, int E, int NB, int eb) {
  __shared__ int smem[1024];
  const int bx = blockIdx.x;
  if (bx < 768) {
    int ty = bx >> 8, k = bx & 255, n = threadIdx.x;
    const float* W = ty == 0 ? W0 : (ty == 1 ? W1 : W2);
    Wt[((size_t)ty * DIM + n) * DIM + k] = f2bf(W[k * DIM + n]);
    return;
  }
  int e2 = bx - 768;
  int ty = e2 / eb, bxx = e2 % eb;
  const int* rr = ty == 0 ? r0 : (ty == 1 ? r1 : r2);
  const int* cc = ty == 0 ? c0 : (ty == 1 ? c1 : c2);
  bin_edges_body(bxx, ty, smem, smem + 512, rr, cc, bcnt, pairs, E, NB);
}

// überB: bucket_sort (3*NB blocks, FIRST) ∥ gemm3 (gemm_blocks, LAST).
// bsort-first lets the long gemm blocks spread evenly and shortens the tail.
__global__ __launch_bounds__(256, 2) void compute_kernel(
    const float* __restrict__ H, const unsigned short* __restrict__ Wt,
    const float* __restrict__ a0, const float* __restrict__ a1,
    const float* __restrict__ a2, unsigned short* __restrict__ Whb,
    float* __restrict__ s_dst, float* __restrict__ s_src, int N, size_t wstride,
    const int* __restrict__ bcnt, unsigned* __restrict__ pairs,
    int* __restrict__ rp, int* __restrict__ deg, int NB, int sort_blocks) {
  __shared__ __align__(16) char smem[76032];
  const int bx = blockIdx.x;
  if (bx < sort_blocks) {
    bsort_body(bx % NB, bx / NB, smem, bcnt, pairs, rp, deg, N, NB);
  } else {
    gemm3_body(bx - sort_blocks, smem, H, Wt, a0, a1, a2, Whb, s_dst, s_src, N, wstride);
  }
}

// standalone bucket_sort (fallback path)
__global__ __launch_bounds__(256) void bucket_sort_kernel(
    const int* __restrict__ bcnt, unsigned* __restrict__ pairs,
    int* __restrict__ rp, int* __restrict__ deg, int N, int NB) {
  __shared__ __align__(16) char smem[39936];
  bsort_body(blockIdx.x, blockIdx.y, smem, bcnt, pairs, rp, deg, N, NB);
}

// per-type gemm (fallback path) — round-3 verified
__global__ __launch_bounds__(256, 2) void gemm_scores_kernel(
    const float* __restrict__ H, const unsigned short* __restrict__ Wt,
    const float* __restrict__ a, unsigned short* __restrict__ Whb,
    float* __restrict__ s_dst, float* __restrict__ s_src, int N) {
  __shared__ unsigned short Hs[64][264];
  __shared__ unsigned short Os[4][16][264];
  const int t = threadIdx.x;
  const int r0 = blockIdx.x * 64;
#pragma unroll
  for (int i = 0; i < 16; ++i) {
    int idx = t + i * 256;
    int row = idx >> 6;
    int c4 = idx & 63;
    int r = r0 + row;
    float4 h = (r < N) ? *(const float4*)&H[(size_t)r * DIM + c4 * 4]
                       : make_float4(0.f, 0.f, 0.f, 0.f);
    unsigned lo = (unsigned)f2bf(h.x) | ((unsigned)f2bf(h.y) << 16);
    unsigned hi = (unsigned)f2bf(h.z) | ((unsigned)f2bf(h.w) << 16);
    *(uint2*)&Hs[row][c4 * 4] = make_uint2(lo, hi);
  }
  __syncthreads();
  const int wave = t >> 6, lane = t & 63;
  const int q = lane >> 4, m = lane & 15;
  const int rowbase = wave * 16;
  short8 Af[8];
#pragma unroll
  for (int k0 = 0; k0 < 8; ++k0)
    Af[k0] = *(const short8*)&Hs[rowbase + m][k0 * 32 + q * 8];
  f32x4 acc[16];
#pragma unroll
  for (int j = 0; j < 16; ++j) acc[j] = (f32x4){0.f, 0.f, 0.f, 0.f};
#pragma unroll
  for (int k0 = 0; k0 < 8; ++k0) {
#pragma unroll
    for (int j = 0; j < 16; ++j) {
      short8 Bf = *(const short8*)&Wt[(size_t)(j * 16 + m) * DIM + k0 * 32 + q * 8];
      acc[j] = __builtin_amdgcn_mfma_f32_16x16x32_bf16(Af[k0], Bf, acc[j], 0, 0, 0);
    }
  }
  float pd[4] = {0, 0, 0, 0}, ps[4] = {0, 0, 0, 0};
#pragma unroll
  for (int j = 0; j < 16; ++j) {
    int col = j * 16 + m;
    float ad = a[col], as = a[DIM + col];
#pragma unroll
    for (int reg = 0; reg < 4; ++reg) {
      float v = acc[j][reg];
      pd[reg] += v * ad;
      ps[reg] += v * as;
      Os[wave][q * 4 + reg][col] = f2bf(v);
    }
  }
#pragma unroll
  for (int off = 8; off >= 1; off >>= 1) {
#pragma unroll
    for (int reg = 0; reg < 4; ++reg) {
      pd[reg] += __shfl_down(pd[reg], off);
      ps[reg] += __shfl_down(ps[reg], off);
    }
  }
  if (m == 0) {
#pragma unroll
    for (int reg = 0; reg < 4; ++reg) {
      int r = r0 + rowbase + q * 4 + reg;
      if (r < N) {
        s_dst[r] = pd[reg];
        s_src[r] = ps[reg];
      }
    }
  }
  __syncthreads();
#pragma unroll
  for (int row = 0; row < 16; ++row) {
    int r = r0 + rowbase + row;
    if (r < N)
      *(uint2*)&Whb[(size_t)r * DIM + lane * 4] = *(const uint2*)&Os[wave][row][lane * 4];
  }
}

// FUSED gat (round-5 verified best): one wave per destination node, all 3
// types in-register, single out write (bias folded).
__global__ __launch_bounds__(256) void gat_fused_kernel(
    const int* __restrict__ rp, const int* __restrict__ deg,
    const unsigned* __restrict__ pairs,
    const float* __restrict__ s_dst, const float* __restrict__ s_src,
    const unsigned short* __restrict__ Whb,
    const float* __restrict__ bias, float* __restrict__ out, int N, int NB,
    size_t wstride) {
  __shared__ uint2 ebuf[4][64];  // per-wave parked (col, exp-weight)
  int n = (int)((blockIdx.x * (unsigned)blockDim.x + threadIdx.x) >> 6);
  if (n >= N) return;
  const int wid = (threadIdx.x >> 6);
  const int lane = threadIdx.x & 63;
  float4 total = {0.f, 0.f, 0.f, 0.f};
  for (int t = 0; t < 3; ++t) {
    int beg = rp[(size_t)t * N + n], d = deg[(size_t)t * N + n];
    if (d == 0) continue;
    int end = beg + d;
    const unsigned* pcol = pairs + (size_t)t * NB * SLOTS;
    const float* ss = s_src + (size_t)t * N;
    float sd = s_dst[(size_t)t * N + n];
    const unsigned short* wbase = Whb + (size_t)t * wstride + lane * 4;
    // pass A: segment max (lane-parallel)
    float mx = -__builtin_inff();
    for (int p = beg + lane; p < end; p += 64) {
      float v = sd + ss[pcol[p] & 0x1FFFFu];
      v = v > 0.f ? v : SLOPE * v;
      mx = fmaxf(mx, v);
    }
#pragma unroll
    for (int off = 32; off >= 1; off >>= 1) mx = fmaxf(mx, __shfl_down(mx, off));
    mx = __shfl(mx, 0);
    // pass B: chunk of 64 edges -> lane-parallel exp, then unrolled gather+FMA
    float4 acc = {0.f, 0.f, 0.f, 0.f};
    float psum = 0.f;
    for (int base = beg; base < end; base += 64) {
      int myp = base + lane;
      int cnt = end - base;
      if (cnt > 64) cnt = 64;
      unsigned myc = 0;
      float mype = 0.f;
      if (myp < end) {
        myc = pcol[myp] & 0x1FFFFu;
        float v = sd + ss[myc];
        v = v > 0.f ? v : SLOPE * v;
        mype = __expf(v - mx);
      }
      psum += mype;
      ebuf[wid][lane] = make_uint2(myc, __float_as_uint(mype));
      // same-wave LDS RAW: compiler inserts lgkmcnt; no barrier needed
#pragma unroll 8
      for (int j = 0; j < cnt; ++j) {
        uint2 cp = ebuf[wid][j];  // uniform addr: broadcast, conflict-free
        float pe = __uint_as_float(cp.y);
        ushort4 w = *(const ushort4*)&wbase[(size_t)cp.x * DIM];
        acc.x += pe * bf2f(w.x);
        acc.y += pe * bf2f(w.y);
        acc.z += pe * bf2f(w.z);
        acc.w += pe * bf2f(w.w);
      }
    }
#pragma unroll
    for (int off = 32; off >= 1; off >>= 1) psum += __shfl_down(psum, off);
    psum = __shfl(psum, 0);
    float inv = 1.f / fmaxf(psum, 1e-12f);
    total.x += acc.x * inv;
    total.y += acc.y * inv;
    total.z += acc.z * inv;
    total.w += acc.w * inv;
  }
  float4 cur = ((const float4*)bias)[lane];
  cur.x += total.x;
  cur.y += total.y;
  cur.z += total.z;
  cur.w += total.w;
  *((float4*)(out + (size_t)n * DIM) + lane) = cur;
}

// per-type gat (fallback path when workspace is small) — round-3 verified
__global__ __launch_bounds__(256) void gat_node_kernel(
    const int* __restrict__ rp, const int* __restrict__ deg,
    const unsigned* __restrict__ pcol,
    const float* __restrict__ s_dst, const float* __restrict__ s_src,
    const unsigned short* __restrict__ Whb,
    const float* __restrict__ bias, float* __restrict__ out, int N, int first) {
  __shared__ uint2 ebuf[4][64];
  int n = (int)((blockIdx.x * (unsigned)blockDim.x + threadIdx.x) >> 6);
  if (n >= N) return;
  const int wid = (threadIdx.x >> 6);
  const int lane = threadIdx.x & 63;
  int beg = rp[n], d = deg[n], end = beg + d;
  if (!first && d == 0) return;
  float sd = s_dst[n];
  float mx = -__builtin_inff();
  for (int p = beg + lane; p < end; p += 64) {
    float v = sd + s_src[pcol[p] & 0x1FFFFu];
    v = v > 0.f ? v : SLOPE * v;
    mx = fmaxf(mx, v);
  }
#pragma unroll
  for (int off = 32; off >= 1; off >>= 1) mx = fmaxf(mx, __shfl_down(mx, off));
  mx = __shfl(mx, 0);
  const unsigned short* wbase = Whb + lane * 4;
  float4 acc = {0.f, 0.f, 0.f, 0.f};
  float psum = 0.f;
  for (int base = beg; base < end; base += 64) {
    int myp = base + lane;
    int cnt = end - base;
    if (cnt > 64) cnt = 64;
    unsigned myc = 0;
    float mype = 0.f;
    if (myp < end) {
      myc = pcol[myp] & 0x1FFFFu;
      float v = sd + s_src[myc];
      v = v > 0.f ? v : SLOPE * v;
      mype = __expf(v - mx);
    }
    psum += mype;
    ebuf[wid][lane] = make_uint2(myc, __float_as_uint(mype));
#pragma unroll 8
    for (int j = 0; j < cnt; ++j) {
      uint2 cp = ebuf[wid][j];
      float pe = __uint_as_float(cp.y);
      ushort4 w = *(const ushort4*)&wbase[(size_t)cp.x * DIM];
      acc.x += pe * bf2f(w.x);
      acc.y += pe * bf2f(w.y);
      acc.z += pe * bf2f(w.z);
      acc.w += pe * bf2f(w.w);
    }
  }
#pragma unroll
  for (int off = 32; off >= 1; off >>= 1) psum += __shfl_down(psum, off);
  psum = __shfl(psum, 0);
  float inv = 1.f / fmaxf(psum, 1e-12f);
  float4* o = (float4*)(out + (size_t)n * DIM) + lane;
  float4 cur = first ? ((const float4*)bias)[lane] : *o;
  cur.x += acc.x * inv;
  cur.y += acc.y * inv;
  cur.z += acc.z * inv;
  cur.w += acc.w * inv;
  *o = cur;
}

static inline size_t align256(size_t x) { return (x + 255) & ~(size_t)255; }

extern "C" void kernel_launch(void* const* d_in, const int* in_sizes, int n_in,
                              void* d_out, int out_size, void* d_ws, size_t ws_size,
                              hipStream_t stream) {
  const float* H = (const float*)d_in[0];
  const float* W[3] = {(const float*)d_in[1], (const float*)d_in[2], (const float*)d_in[3]};
  const float* a[3] = {(const float*)d_in[4], (const float*)d_in[5], (const float*)d_in[6]};
  const float* bias = (const float*)d_in[7];
  const int* row[3] = {(const int*)d_in[8], (const int*)d_in[10], (const int*)d_in[12]};
  const int* col[3] = {(const int*)d_in[9], (const int*)d_in[11], (const int*)d_in[13]};
  const int N = in_sizes[0] / DIM;
  const int E = in_sizes[8];
  const int NB = (N + 255) >> BSHIFT;  // 391 for N=100000 (must be <= 512)
  float* out = (float*)d_out;

  char* ws = (char*)d_ws;
  size_t off = 0;
  unsigned short* Wt = (unsigned short*)(ws + off);
  off = align256(off + (size_t)3 * DIM * DIM * sizeof(unsigned short));
  float* s_dst = (float*)(ws + off);  // [3][N]
  off = align256(off + (size_t)3 * N * sizeof(float));
  float* s_src = (float*)(ws + off);  // [3][N]
  off = align256(off + (size_t)3 * N * sizeof(float));
  int* bcnt = (int*)(ws + off);
  off = align256(off + (size_t)3 * NB * sizeof(int));
  int* rp = (int*)(ws + off);
  off = align256(off + (size_t)3 * N * sizeof(int));
  int* deg = (int*)(ws + off);
  off = align256(off + (size_t)3 * N * sizeof(int));
  unsigned* pairs = (unsigned*)(ws + off);
  off = align256(off + (size_t)3 * NB * SLOTS * sizeof(unsigned));
  unsigned short* Whb = (unsigned short*)(ws + off);
  const size_t whb_bytes = align256((size_t)N * DIM * sizeof(unsigned short));
  const size_t wstride = whb_bytes / sizeof(unsigned short);
  const int fused = (ws_size >= off + 3 * whb_bytes) ? 1 : 0;

  const int eb = (E + TILE - 1) / TILE;
  hipMemsetAsync(bcnt, 0, (size_t)3 * NB * sizeof(int), stream);
  prep_kernel<<<768 + 3 * eb, 256, 0, stream>>>(W[0], W[1], W[2], Wt, row[0], row[1], row[2],
                                                col[0], col[1], col[2], bcnt, pairs, E, NB, eb);

  const int gat_blocks = (N * 64 + 255) / 256;
  if (fused) {
    const int nb128 = (N + 127) / 128;
    compute_kernel<<<nb128 + 3 * NB, 256, 0, stream>>>(
        H, Wt, a[0], a[1], a[2], Whb, s_dst, s_src, N, wstride, bcnt, pairs, rp, deg, NB,
        3 * NB /* bsort blocks first */);
    gat_fused_kernel<<<gat_blocks, 256, 0, stream>>>(rp, deg, pairs, s_dst, s_src, Whb, bias,
                                                     out, N, NB, wstride);
  } else {
    bucket_sort_kernel<<<dim3(NB, 3), 256, 0, stream>>>(bcnt, pairs, rp, deg, N, NB);
    for (int t = 0; t < 3; ++t) {
      gemm_scores_kernel<<<(N + 63) / 64, 256, 0, stream>>>(H, Wt + (size_t)t * DIM * DIM,
                                                            a[t], Whb, s_dst + (size_t)t * N,
                                                            s_src + (size_t)t * N, N);
      gat_node_kernel<<<gat_blocks, 256, 0, stream>>>(
          rp + (size_t)t * N, deg + (size_t)t * N, pairs + (size_t)t * NB * SLOTS,
          s_dst + (size_t)t * N, s_src + (size_t)t * N, Whb, bias, out, N, t == 0 ? 1 : 0);
    }
  }
  (void)n_in;
  (void)out_size;
  (void)ws_size;
}

// Round 13
// 1370.537 us; speedup vs baseline: 2.1440x; 1.0329x over previous
//
#include <hip/hip_runtime.h>
#include <cstdint>
#include <cstddef>

#define DIM 256
#define SLOPE 0.2f
#define BSHIFT 8          // 256 rows per bucket
#define SLOTS 9216        // per-bucket capacity: mean 8192 + ~11 sigma slack
#define TILE 4096         // edges per bin_edges block

typedef __attribute__((ext_vector_type(8))) short short8;  // 8 bf16 (4 VGPRs)
typedef __attribute__((ext_vector_type(4))) float f32x4;   // 4 fp32

__device__ __forceinline__ unsigned short f2bf(float f) {  // RNE fp32->bf16
  unsigned u = __float_as_uint(f);
  u += 0x7fffu + ((u >> 16) & 1u);
  return (unsigned short)(u >> 16);
}
__device__ __forceinline__ float bf2f(unsigned short h) {
  return __uint_as_float(((unsigned)h) << 16);
}

// ---------------- bodies ----------------

__device__ __forceinline__ void bin_edges_body(
    int bx, int ty, int* hist, int* curs, const int* __restrict__ rr,
    const int* __restrict__ cc, int* __restrict__ bcnt, unsigned* __restrict__ pairs,
    int E, int NB) {
  const int t = threadIdx.x;
  const int base = bx * TILE;
  for (int i = t; i < NB; i += 256) hist[i] = 0;
  __syncthreads();
  int rows[TILE / 256];
#pragma unroll
  for (int i = 0; i < TILE / 256; ++i) {
    int e = base + t + i * 256;
    int r = (e < E) ? __builtin_nontemporal_load(&rr[e]) : -1;  // read-once stream
    rows[i] = r;
    if (r >= 0) atomicAdd(&hist[r >> BSHIFT], 1);
  }
  __syncthreads();
  for (int b = t; b < NB; b += 256) {
    int h = hist[b];
    int off = h ? atomicAdd(&bcnt[ty * NB + b], h) : 0;
    curs[b] = b * SLOTS + off;
  }
  __syncthreads();
  unsigned* pt = pairs + (size_t)ty * NB * SLOTS;
#pragma unroll
  for (int i = 0; i < TILE / 256; ++i) {
    int e = base + t + i * 256;
    if (e >= E) continue;
    int r = rows[i];
    int b = r >> BSHIFT;
    int pos = atomicAdd(&curs[b], 1);
    if (pos - b * SLOTS < SLOTS)
      pt[pos] = ((unsigned)(r & 255) << 17) |
                (unsigned)__builtin_nontemporal_load(&cc[e]);
  }
}

__device__ __forceinline__ void bsort_body(
    int b, int ty, char* smem, const int* __restrict__ bcnt,
    unsigned* __restrict__ pairs, int* __restrict__ rp, int* __restrict__ deg,
    int N, int NB) {
  int* hist = (int*)smem;
  int* excl = hist + 256;
  int* curs = excl + 256;
  unsigned* stage = (unsigned*)(curs + 256);
  const int t = threadIdx.x;
  int cnt = bcnt[ty * NB + b];
  if (cnt > SLOTS) cnt = SLOTS;
  unsigned* pb = pairs + (size_t)ty * NB * SLOTS + (size_t)b * SLOTS;
  hist[t] = 0;
  __syncthreads();
  for (int i = t; i < cnt; i += 256) atomicAdd(&hist[pb[i] >> 17], 1);
  __syncthreads();
  int v = hist[t];
  excl[t] = v;
  __syncthreads();
  for (int off = 1; off < 256; off <<= 1) {
    int u = (t >= off) ? excl[t - off] : 0;
    __syncthreads();
    excl[t] += u;
    __syncthreads();
  }
  int ex = excl[t] - v;
  curs[t] = ex;
  int r = (b << BSHIFT) + t;
  if (r < N) {
    rp[(size_t)ty * N + r] = b * SLOTS + ex;
    deg[(size_t)ty * N + r] = v;
  }
  __syncthreads();
  for (int i = t; i < cnt; i += 256) {
    unsigned p = pb[i];
    int pos = atomicAdd(&curs[p >> 17], 1);
    stage[pos] = p;
  }
  __syncthreads();
  for (int i = t; i < cnt; i += 256) pb[i] = stage[i];
}

// gemm3 v2 body: 128-row tile, 4 waves x 32 rows/wave, 2 MFMA per B-load.
// H loads are nontemporal (read-once stream; keep L3 free for Whb).
__device__ __forceinline__ void gemm3_body(
    int bx, char* smem, const float* __restrict__ H, const unsigned short* __restrict__ Wt,
    const float* __restrict__ a0, const float* __restrict__ a1,
    const float* __restrict__ a2, unsigned short* __restrict__ Whb,
    float* __restrict__ s_dst, float* __restrict__ s_src, int N, size_t wstride) {
  unsigned short(*Hs)[264] = (unsigned short(*)[264])smem;
  unsigned short(*Os)[4][264] = (unsigned short(*)[4][264])(smem + 128 * 264 * 2);
  const int t = threadIdx.x;
  const int r0 = bx * 128;
#pragma unroll
  for (int i = 0; i < 32; ++i) {
    int idx = t + i * 256;
    int row = idx >> 6;
    int c4 = idx & 63;
    int r = r0 + row;
    f32x4 h = (f32x4){0.f, 0.f, 0.f, 0.f};
    if (r < N) h = __builtin_nontemporal_load((const f32x4*)&H[(size_t)r * DIM + c4 * 4]);
    unsigned lo = (unsigned)f2bf(h[0]) | ((unsigned)f2bf(h[1]) << 16);
    unsigned hi = (unsigned)f2bf(h[2]) | ((unsigned)f2bf(h[3]) << 16);
    *(uint2*)&Hs[row][c4 * 4] = make_uint2(lo, hi);
  }
  __syncthreads();
  const int wave = t >> 6, lane = t & 63;
  const int q = lane >> 4, m = lane & 15;
  const int rowbase = wave * 32;
  short8 Af0[8], Af1[8];
#pragma unroll
  for (int k0 = 0; k0 < 8; ++k0) {
    Af0[k0] = *(const short8*)&Hs[rowbase + m][k0 * 32 + q * 8];
    Af1[k0] = *(const short8*)&Hs[rowbase + 16 + m][k0 * 32 + q * 8];
  }
  const float* aptr[3] = {a0, a1, a2};
  for (int ty = 0; ty < 3; ++ty) {
    const unsigned short* Wtt = Wt + (size_t)ty * DIM * DIM;
    const float* a = aptr[ty];
    f32x4 acc0[16], acc1[16];
#pragma unroll
    for (int j = 0; j < 16; ++j) {
      acc0[j] = (f32x4){0.f, 0.f, 0.f, 0.f};
      acc1[j] = (f32x4){0.f, 0.f, 0.f, 0.f};
    }
#pragma unroll
    for (int k0 = 0; k0 < 8; ++k0) {
#pragma unroll
      for (int j = 0; j < 16; ++j) {
        short8 Bf = *(const short8*)&Wtt[(size_t)(j * 16 + m) * DIM + k0 * 32 + q * 8];
        acc0[j] = __builtin_amdgcn_mfma_f32_16x16x32_bf16(Af0[k0], Bf, acc0[j], 0, 0, 0);
        acc1[j] = __builtin_amdgcn_mfma_f32_16x16x32_bf16(Af1[k0], Bf, acc1[j], 0, 0, 0);
      }
    }
    float pd0[4] = {0, 0, 0, 0}, ps0[4] = {0, 0, 0, 0};
    float pd1[4] = {0, 0, 0, 0}, ps1[4] = {0, 0, 0, 0};
#pragma unroll
    for (int j = 0; j < 16; ++j) {
      int col = j * 16 + m;
      float ad = a[col], as = a[DIM + col];
#pragma unroll
      for (int reg = 0; reg < 4; ++reg) {
        float v0 = acc0[j][reg], v1 = acc1[j][reg];
        pd0[reg] += v0 * ad;
        ps0[reg] += v0 * as;
        pd1[reg] += v1 * ad;
        ps1[reg] += v1 * as;
      }
    }
#pragma unroll
    for (int off = 8; off >= 1; off >>= 1) {
#pragma unroll
      for (int reg = 0; reg < 4; ++reg) {
        pd0[reg] += __shfl_down(pd0[reg], off);
        ps0[reg] += __shfl_down(ps0[reg], off);
        pd1[reg] += __shfl_down(pd1[reg], off);
        ps1[reg] += __shfl_down(ps1[reg], off);
      }
    }
    if (m == 0) {
#pragma unroll
      for (int reg = 0; reg < 4; ++reg) {
        int ra = r0 + rowbase + q * 4 + reg;
        int rb = ra + 16;
        if (ra < N) {
          s_dst[(size_t)ty * N + ra] = pd0[reg];
          s_src[(size_t)ty * N + ra] = ps0[reg];
        }
        if (rb < N) {
          s_dst[(size_t)ty * N + rb] = pd1[reg];
          s_src[(size_t)ty * N + rb] = ps1[reg];
        }
      }
    }
    unsigned short* wout = Whb + (size_t)ty * wstride;
#pragma unroll
    for (int g = 0; g < 2; ++g) {
#pragma unroll
      for (int p = 0; p < 4; ++p) {
        if (q == p) {
#pragma unroll
          for (int j = 0; j < 16; ++j)
#pragma unroll
            for (int reg = 0; reg < 4; ++reg)
              Os[wave][reg][j * 16 + m] = f2bf(g ? acc1[j][reg] : acc0[j][reg]);
        }
#pragma unroll
        for (int rr = 0; rr < 4; ++rr) {
          int r = r0 + rowbase + g * 16 + p * 4 + rr;
          if (r < N)
            *(uint2*)&wout[(size_t)r * DIM + lane * 4] =
                *(const uint2*)&Os[wave][rr][lane * 4];
        }
      }
    }
  }
}

// ---------------- über kernels ----------------

// überA: wtrans (768 blocks) ∥ bin_edges (3*eb blocks)
__global__ __launch_bounds__(256) void prep_kernel(
    const float* __restrict__ W0, const float* __restrict__ W1,
    const float* __restrict__ W2, unsigned short* __restrict__ Wt,
    const int* __restrict__ r0, const int* __restrict__ r1, const int* __restrict__ r2,
    const int* __restrict__ c0, const int* __restrict__ c1, const int* __restrict__ c2,
    int* __restrict__ bcnt, unsigned* __restrict__ pairs, int E, int NB, int eb) {
  __shared__ int smem[1024];
  const int bx = blockIdx.x;
  if (bx < 768) {
    int ty = bx >> 8, k = bx & 255, n = threadIdx.x;
    const float* W = ty == 0 ? W0 : (ty == 1 ? W1 : W2);
    Wt[((size_t)ty * DIM + n) * DIM + k] = f2bf(W[k * DIM + n]);
    return;
  }
  int e2 = bx - 768;
  int ty = e2 / eb, bxx = e2 % eb;
  const int* rr = ty == 0 ? r0 : (ty == 1 ? r1 : r2);
  const int* cc = ty == 0 ? c0 : (ty == 1 ? c1 : c2);
  bin_edges_body(bxx, ty, smem, smem + 512, rr, cc, bcnt, pairs, E, NB);
}

// überB: gemm3 (gemm_blocks, FIRST — R10-verified order) ∥ bucket_sort.
__global__ __launch_bounds__(256, 2) void compute_kernel(
    const float* __restrict__ H, const unsigned short* __restrict__ Wt,
    const float* __restrict__ a0, const float* __restrict__ a1,
    const float* __restrict__ a2, unsigned short* __restrict__ Whb,
    float* __restrict__ s_dst, float* __restrict__ s_src, int N, size_t wstride,
    const int* __restrict__ bcnt, unsigned* __restrict__ pairs,
    int* __restrict__ rp, int* __restrict__ deg, int NB, int gemm_blocks) {
  __shared__ __align__(16) char smem[76032];
  const int bx = blockIdx.x;
  if (bx < gemm_blocks) {
    gemm3_body(bx, smem, H, Wt, a0, a1, a2, Whb, s_dst, s_src, N, wstride);
  } else {
    int e = bx - gemm_blocks;
    bsort_body(e % NB, e / NB, smem, bcnt, pairs, rp, deg, N, NB);
  }
}

// standalone bucket_sort (fallback path)
__global__ __launch_bounds__(256) void bucket_sort_kernel(
    const int* __restrict__ bcnt, unsigned* __restrict__ pairs,
    int* __restrict__ rp, int* __restrict__ deg, int N, int NB) {
  __shared__ __align__(16) char smem[39936];
  bsort_body(blockIdx.x, blockIdx.y, smem, bcnt, pairs, rp, deg, N, NB);
}

// per-type gemm (fallback path) — round-3 verified
__global__ __launch_bounds__(256, 2) void gemm_scores_kernel(
    const float* __restrict__ H, const unsigned short* __restrict__ Wt,
    const float* __restrict__ a, unsigned short* __restrict__ Whb,
    float* __restrict__ s_dst, float* __restrict__ s_src, int N) {
  __shared__ unsigned short Hs[64][264];
  __shared__ unsigned short Os[4][16][264];
  const int t = threadIdx.x;
  const int r0 = blockIdx.x * 64;
#pragma unroll
  for (int i = 0; i < 16; ++i) {
    int idx = t + i * 256;
    int row = idx >> 6;
    int c4 = idx & 63;
    int r = r0 + row;
    float4 h = (r < N) ? *(const float4*)&H[(size_t)r * DIM + c4 * 4]
                       : make_float4(0.f, 0.f, 0.f, 0.f);
    unsigned lo = (unsigned)f2bf(h.x) | ((unsigned)f2bf(h.y) << 16);
    unsigned hi = (unsigned)f2bf(h.z) | ((unsigned)f2bf(h.w) << 16);
    *(uint2*)&Hs[row][c4 * 4] = make_uint2(lo, hi);
  }
  __syncthreads();
  const int wave = t >> 6, lane = t & 63;
  const int q = lane >> 4, m = lane & 15;
  const int rowbase = wave * 16;
  short8 Af[8];
#pragma unroll
  for (int k0 = 0; k0 < 8; ++k0)
    Af[k0] = *(const short8*)&Hs[rowbase + m][k0 * 32 + q * 8];
  f32x4 acc[16];
#pragma unroll
  for (int j = 0; j < 16; ++j) acc[j] = (f32x4){0.f, 0.f, 0.f, 0.f};
#pragma unroll
  for (int k0 = 0; k0 < 8; ++k0) {
#pragma unroll
    for (int j = 0; j < 16; ++j) {
      short8 Bf = *(const short8*)&Wt[(size_t)(j * 16 + m) * DIM + k0 * 32 + q * 8];
      acc[j] = __builtin_amdgcn_mfma_f32_16x16x32_bf16(Af[k0], Bf, acc[j], 0, 0, 0);
    }
  }
  float pd[4] = {0, 0, 0, 0}, ps[4] = {0, 0, 0, 0};
#pragma unroll
  for (int j = 0; j < 16; ++j) {
    int col = j * 16 + m;
    float ad = a[col], as = a[DIM + col];
#pragma unroll
    for (int reg = 0; reg < 4; ++reg) {
      float v = acc[j][reg];
      pd[reg] += v * ad;
      ps[reg] += v * as;
      Os[wave][q * 4 + reg][col] = f2bf(v);
    }
  }
#pragma unroll
  for (int off = 8; off >= 1; off >>= 1) {
#pragma unroll
    for (int reg = 0; reg < 4; ++reg) {
      pd[reg] += __shfl_down(pd[reg], off);
      ps[reg] += __shfl_down(ps[reg], off);
    }
  }
  if (m == 0) {
#pragma unroll
    for (int reg = 0; reg < 4; ++reg) {
      int r = r0 + rowbase + q * 4 + reg;
      if (r < N) {
        s_dst[r] = pd[reg];
        s_src[r] = ps[reg];
      }
    }
  }
  __syncthreads();
#pragma unroll
  for (int row = 0; row < 16; ++row) {
    int r = r0 + rowbase + row;
    if (r < N)
      *(uint2*)&Whb[(size_t)r * DIM + lane * 4] = *(const uint2*)&Os[wave][row][lane * 4];
  }
}

// FUSED gat (round-5 verified best) + nontemporal out store.
__global__ __launch_bounds__(256) void gat_fused_kernel(
    const int* __restrict__ rp, const int* __restrict__ deg,
    const unsigned* __restrict__ pairs,
    const float* __restrict__ s_dst, const float* __restrict__ s_src,
    const unsigned short* __restrict__ Whb,
    const float* __restrict__ bias, float* __restrict__ out, int N, int NB,
    size_t wstride) {
  __shared__ uint2 ebuf[4][64];  // per-wave parked (col, exp-weight)
  int n = (int)((blockIdx.x * (unsigned)blockDim.x + threadIdx.x) >> 6);
  if (n >= N) return;
  const int wid = (threadIdx.x >> 6);
  const int lane = threadIdx.x & 63;
  float4 total = {0.f, 0.f, 0.f, 0.f};
  for (int t = 0; t < 3; ++t) {
    int beg = rp[(size_t)t * N + n], d = deg[(size_t)t * N + n];
    if (d == 0) continue;
    int end = beg + d;
    const unsigned* pcol = pairs + (size_t)t * NB * SLOTS;
    const float* ss = s_src + (size_t)t * N;
    float sd = s_dst[(size_t)t * N + n];
    const unsigned short* wbase = Whb + (size_t)t * wstride + lane * 4;
    // pass A: segment max (lane-parallel)
    float mx = -__builtin_inff();
    for (int p = beg + lane; p < end; p += 64) {
      float v = sd + ss[pcol[p] & 0x1FFFFu];
      v = v > 0.f ? v : SLOPE * v;
      mx = fmaxf(mx, v);
    }
#pragma unroll
    for (int off = 32; off >= 1; off >>= 1) mx = fmaxf(mx, __shfl_down(mx, off));
    mx = __shfl(mx, 0);
    // pass B: chunk of 64 edges -> lane-parallel exp, then unrolled gather+FMA
    float4 acc = {0.f, 0.f, 0.f, 0.f};
    float psum = 0.f;
    for (int base = beg; base < end; base += 64) {
      int myp = base + lane;
      int cnt = end - base;
      if (cnt > 64) cnt = 64;
      unsigned myc = 0;
      float mype = 0.f;
      if (myp < end) {
        myc = pcol[myp] & 0x1FFFFu;
        float v = sd + ss[myc];
        v = v > 0.f ? v : SLOPE * v;
        mype = __expf(v - mx);
      }
      psum += mype;
      ebuf[wid][lane] = make_uint2(myc, __float_as_uint(mype));
      // same-wave LDS RAW: compiler inserts lgkmcnt; no barrier needed
#pragma unroll 8
      for (int j = 0; j < cnt; ++j) {
        uint2 cp = ebuf[wid][j];  // uniform addr: broadcast, conflict-free
        float pe = __uint_as_float(cp.y);
        ushort4 w = *(const ushort4*)&wbase[(size_t)cp.x * DIM];
        acc.x += pe * bf2f(w.x);
        acc.y += pe * bf2f(w.y);
        acc.z += pe * bf2f(w.z);
        acc.w += pe * bf2f(w.w);
      }
    }
#pragma unroll
    for (int off = 32; off >= 1; off >>= 1) psum += __shfl_down(psum, off);
    psum = __shfl(psum, 0);
    float inv = 1.f / fmaxf(psum, 1e-12f);
    total.x += acc.x * inv;
    total.y += acc.y * inv;
    total.z += acc.z * inv;
    total.w += acc.w * inv;
  }
  float4 bv = ((const float4*)bias)[lane];
  f32x4 cur;
  cur[0] = bv.x + total.x;
  cur[1] = bv.y + total.y;
  cur[2] = bv.z + total.z;
  cur[3] = bv.w + total.w;
  // nontemporal: out is write-once, never re-read -> don't evict Whb from L3
  __builtin_nontemporal_store(cur, (f32x4*)(out + (size_t)n * DIM) + lane);
}

// per-type gat (fallback path when workspace is small) — round-3 verified
__global__ __launch_bounds__(256) void gat_node_kernel(
    const int* __restrict__ rp, const int* __restrict__ deg,
    const unsigned* __restrict__ pcol,
    const float* __restrict__ s_dst, const float* __restrict__ s_src,
    const unsigned short* __restrict__ Whb,
    const float* __restrict__ bias, float* __restrict__ out, int N, int first) {
  __shared__ uint2 ebuf[4][64];
  int n = (int)((blockIdx.x * (unsigned)blockDim.x + threadIdx.x) >> 6);
  if (n >= N) return;
  const int wid = (threadIdx.x >> 6);
  const int lane = threadIdx.x & 63;
  int beg = rp[n], d = deg[n], end = beg + d;
  if (!first && d == 0) return;
  float sd = s_dst[n];
  float mx = -__builtin_inff();
  for (int p = beg + lane; p < end; p += 64) {
    float v = sd + s_src[pcol[p] & 0x1FFFFu];
    v = v > 0.f ? v : SLOPE * v;
    mx = fmaxf(mx, v);
  }
#pragma unroll
  for (int off = 32; off >= 1; off >>= 1) mx = fmaxf(mx, __shfl_down(mx, off));
  mx = __shfl(mx, 0);
  const unsigned short* wbase = Whb + lane * 4;
  float4 acc = {0.f, 0.f, 0.f, 0.f};
  float psum = 0.f;
  for (int base = beg; base < end; base += 64) {
    int myp = base + lane;
    int cnt = end - base;
    if (cnt > 64) cnt = 64;
    unsigned myc = 0;
    float mype = 0.f;
    if (myp < end) {
      myc = pcol[myp] & 0x1FFFFu;
      float v = sd + s_src[myc];
      v = v > 0.f ? v : SLOPE * v;
      mype = __expf(v - mx);
    }
    psum += mype;
    ebuf[wid][lane] = make_uint2(myc, __float_as_uint(mype));
#pragma unroll 8
    for (int j = 0; j < cnt; ++j) {
      uint2 cp = ebuf[wid][j];
      float pe = __uint_as_float(cp.y);
      ushort4 w = *(const ushort4*)&wbase[(size_t)cp.x * DIM];
      acc.x += pe * bf2f(w.x);
      acc.y += pe * bf2f(w.y);
      acc.z += pe * bf2f(w.z);
      acc.w += pe * bf2f(w.w);
    }
  }
#pragma unroll
  for (int off = 32; off >= 1; off >>= 1) psum += __shfl_down(psum, off);
  psum = __shfl(psum, 0);
  float inv = 1.f / fmaxf(psum, 1e-12f);
  float4* o = (float4*)(out + (size_t)n * DIM) + lane;
  float4 cur = first ? ((const float4*)bias)[lane] : *o;
  cur.x += acc.x * inv;
  cur.y += acc.y * inv;
  cur.z += acc.z * inv;
  cur.w += acc.w * inv;
  *o = cur;
}

static inline size_t align256(size_t x) { return (x + 255) & ~(size_t)255; }

extern "C" void kernel_launch(void* const* d_in, const int* in_sizes, int n_in,
                              void* d_out, int out_size, void* d_ws, size_t ws_size,
                              hipStream_t stream) {
  const float* H = (const float*)d_in[0];
  const float* W[3] = {(const float*)d_in[1], (const float*)d_in[2], (const float*)d_in[3]};
  const float* a[3] = {(const float*)d_in[4], (const float*)d_in[5], (const float*)d_in[6]};
  const float* bias = (const float*)d_in[7];
  const int* row[3] = {(const int*)d_in[8], (const int*)d_in[10], (const int*)d_in[12]};
  const int* col[3] = {(const int*)d_in[9], (const int*)d_in[11], (const int*)d_in[13]};
  const int N = in_sizes[0] / DIM;
  const int E = in_sizes[8];
  const int NB = (N + 255) >> BSHIFT;  // 391 for N=100000 (must be <= 512)
  float* out = (float*)d_out;

  char* ws = (char*)d_ws;
  size_t off = 0;
  unsigned short* Wt = (unsigned short*)(ws + off);
  off = align256(off + (size_t)3 * DIM * DIM * sizeof(unsigned short));
  float* s_dst = (float*)(ws + off);  // [3][N]
  off = align256(off + (size_t)3 * N * sizeof(float));
  float* s_src = (float*)(ws + off);  // [3][N]
  off = align256(off + (size_t)3 * N * sizeof(float));
  int* bcnt = (int*)(ws + off);
  off = align256(off + (size_t)3 * NB * sizeof(int));
  int* rp = (int*)(ws + off);
  off = align256(off + (size_t)3 * N * sizeof(int));
  int* deg = (int*)(ws + off);
  off = align256(off + (size_t)3 * N * sizeof(int));
  unsigned* pairs = (unsigned*)(ws + off);
  off = align256(off + (size_t)3 * NB * SLOTS * sizeof(unsigned));
  unsigned short* Whb = (unsigned short*)(ws + off);
  const size_t whb_bytes = align256((size_t)N * DIM * sizeof(unsigned short));
  const size_t wstride = whb_bytes / sizeof(unsigned short);
  const int fused = (ws_size >= off + 3 * whb_bytes) ? 1 : 0;

  const int eb = (E + TILE - 1) / TILE;
  hipMemsetAsync(bcnt, 0, (size_t)3 * NB * sizeof(int), stream);
  prep_kernel<<<768 + 3 * eb, 256, 0, stream>>>(W[0], W[1], W[2], Wt, row[0], row[1], row[2],
                                                col[0], col[1], col[2], bcnt, pairs, E, NB, eb);

  const int gat_blocks = (N * 64 + 255) / 256;
  if (fused) {
    const int nb128 = (N + 127) / 128;
    compute_kernel<<<nb128 + 3 * NB, 256, 0, stream>>>(
        H, Wt, a[0], a[1], a[2], Whb, s_dst, s_src, N, wstride, bcnt, pairs, rp, deg, NB,
        nb128 /* gemm blocks first (R10 order) */);
    gat_fused_kernel<<<gat_blocks, 256, 0, stream>>>(rp, deg, pairs, s_dst, s_src, Whb, bias,
                                                     out, N, NB, wstride);
  } else {
    bucket_sort_kernel<<<dim3(NB, 3), 256, 0, stream>>>(bcnt, pairs, rp, deg, N, NB);
    for (int t = 0; t < 3; ++t) {
      gemm_scores_kernel<<<(N + 63) / 64, 256, 0, stream>>>(H, Wt + (size_t)t * DIM * DIM,
                                                            a[t], Whb, s_dst + (size_t)t * N,
                                                            s_src + (size_t)t * N, N);
      gat_node_kernel<<<gat_blocks, 256, 0, stream>>>(
          rp + (size_t)t * N, deg + (size_t)t * N, pairs + (size_t)t * NB * SLOTS,
          s_dst + (size_t)t * N, s_src + (size_t)t * N, Whb, bias, out, N, t == 0 ? 1 : 0);
    }
  }
  (void)n_in;
  (void)out_size;
  (void)ws_size;
}